// Round 9
// baseline (907.511 us; speedup 1.0000x reference)
//
#include <hip/hip_runtime.h>

#define NN 100000
#define NE 1600000
#define HID 64
#define BNODE 128                            // nodes per bucket
#define NBUK ((NN + BNODE - 1) / BNODE)      // 782
#define SRCBITS 17
#define SRCMASK 0x1FFFF
#define EBLK 2048                            // edges per hist/fill block
#define GE2 ((NE + EBLK - 1) / EBLK)         // 782
#define SCANN (NBUK * GE2)                   // 611,524
#define CHUNK 1024
#define NCH ((SCANN + CHUNK - 1) / CHUNK)    // 598
#define APAD 65                              // padded LDS row stride (floats)

__device__ __forceinline__ float bf2f(unsigned short u) {
    return __uint_as_float(((unsigned int)u) << 16);
}
__device__ __forceinline__ unsigned short f2bf(float f) {   // RTNE
    unsigned int x = __float_as_uint(f);
    return (unsigned short)((x + 0x7FFFu + ((x >> 16) & 1u)) >> 16);
}

// ---- detect edge dtype (int64 vs int32) ------------------------------------
__global__ void k_detect(const int* __restrict__ ei, int* __restrict__ flag) {
    int t = threadIdx.x;  // 64
    int v = ei[2 * t + 1];
    unsigned long long b = __ballot(v != 0);
    if (t == 0) *flag = (b == 0ULL) ? 1 : 0;  // 1 => int64 layout
}

__device__ __forceinline__ int ld_idx(const int* __restrict__ ei, int off, int is64) {
    return is64 ? ei[2 * off] : ei[off];
}

// ---- pass A1: per-block bucket histogram (LDS atomics only) ----------------
__global__ void k_histA(const int* __restrict__ ei, const int* __restrict__ flag,
                        int* __restrict__ histG) {
    __shared__ int hist[NBUK];
    int t = threadIdx.x;  // 256
    for (int i = t; i < NBUK; i += 256) hist[i] = 0;
    __syncthreads();
    int f = *flag;
    int base = blockIdx.x * EBLK;
#pragma unroll
    for (int k = 0; k < EBLK / 256; ++k) {
        int e = base + k * 256 + t;
        if (e < NE) {
            int d = ld_idx(ei, NE + e, f);
            atomicAdd(&hist[d >> 7], 1);
        }
    }
    __syncthreads();
    for (int i = t; i < NBUK; i += 256) histG[i * GE2 + blockIdx.x] = hist[i];
}

// ---- 3-stage exclusive scan of SCANN counts --------------------------------
__global__ void k_scan1(int* __restrict__ g, int* __restrict__ bsum) {
    __shared__ int s[256];
    int t = threadIdx.x;
    int i4 = blockIdx.x * 256 + t;
    int base = i4 * 4;
    int4 v = make_int4(0, 0, 0, 0);
    if (base + 3 < SCANN) v = ((const int4*)g)[i4];
    else {
        if (base + 0 < SCANN) v.x = g[base + 0];
        if (base + 1 < SCANN) v.y = g[base + 1];
        if (base + 2 < SCANN) v.z = g[base + 2];
        if (base + 3 < SCANN) v.w = g[base + 3];
    }
    int tsum = v.x + v.y + v.z + v.w;
    s[t] = tsum; __syncthreads();
    for (int off = 1; off < 256; off <<= 1) {
        int u = (t >= off) ? s[t - off] : 0;
        __syncthreads();
        s[t] += u;
        __syncthreads();
    }
    int run = s[t] - tsum;
    int4 o;
    o.x = run; run += v.x;
    o.y = run; run += v.y;
    o.z = run; run += v.z;
    o.w = run;
    if (base + 3 < SCANN) ((int4*)g)[i4] = o;
    else {
        if (base + 0 < SCANN) g[base + 0] = o.x;
        if (base + 1 < SCANN) g[base + 1] = o.y;
        if (base + 2 < SCANN) g[base + 2] = o.z;
        if (base + 3 < SCANN) g[base + 3] = o.w;
    }
    if (t == 255) bsum[blockIdx.x] = s[255];
}

__global__ void k_scan2(int* __restrict__ bsum) {
    __shared__ int s[1024];
    int t = threadIdx.x;  // 1024
    int v = (t < NCH) ? bsum[t] : 0;
    s[t] = v; __syncthreads();
    for (int off = 1; off < 1024; off <<= 1) {
        int u = (t >= off) ? s[t - off] : 0;
        __syncthreads();
        s[t] += u;
        __syncthreads();
    }
    if (t < NCH) bsum[t] = s[t] - v;
}

__global__ void k_scan3(int* __restrict__ g, const int* __restrict__ bsum) {
    int t = threadIdx.x;
    int i4 = blockIdx.x * 256 + t;
    int base = i4 * 4;
    int add = bsum[blockIdx.x];
    if (base + 3 < SCANN) {
        int4 v = ((const int4*)g)[i4];
        v.x += add; v.y += add; v.z += add; v.w += add;
        ((int4*)g)[i4] = v;
    } else {
        if (base + 0 < SCANN) g[base + 0] += add;
        if (base + 1 < SCANN) g[base + 1] += add;
        if (base + 2 < SCANN) g[base + 2] += add;
        if (base + 3 < SCANN) g[base + 3] += add;
    }
}

// ---- pass A2: place packed edges into disjoint per-(block,bucket) ranges ---
__global__ void k_fillA(const int* __restrict__ ei, const int* __restrict__ flag,
                        const int* __restrict__ histS, unsigned int* __restrict__ bbuf) {
    __shared__ int cur[NBUK];
    int t = threadIdx.x;  // 256
    for (int i = t; i < NBUK; i += 256) cur[i] = histS[i * GE2 + blockIdx.x];
    __syncthreads();
    int f = *flag;
    int base = blockIdx.x * EBLK;
#pragma unroll
    for (int k = 0; k < EBLK / 256; ++k) {
        int e = base + k * 256 + t;
        if (e < NE) {
            int s = ld_idx(ei, e, f);
            int d = ld_idx(ei, NE + e, f);
            int p = atomicAdd(&cur[d >> 7], 1);   // LDS atomic
            bbuf[p] = ((unsigned int)(d & 127) << SRCBITS) | (unsigned int)s;
        }
    }
}

// ---- per-bucket degree count -> dinv, xs = dinv * x ------------------------
__global__ void k_cntB(const unsigned int* __restrict__ bbuf, const int* __restrict__ histS,
                       const float* __restrict__ x,
                       float* __restrict__ dinv, float* __restrict__ xs) {
    __shared__ int hist[BNODE];
    int t = threadIdx.x;  // 256
    int b = blockIdx.x;
    if (t < BNODE) hist[t] = 0;
    int base = histS[b * GE2];
    int next = (b == NBUK - 1) ? NE : histS[(b + 1) * GE2];
    __syncthreads();
    for (int e = base + t; e < next; e += 256)
        atomicAdd(&hist[bbuf[e] >> SRCBITS], 1);
    __syncthreads();
    int g = b * BNODE + t;
    if (t < BNODE && g < NN) {
        float d = 1.0f / sqrtf((float)(hist[t] + 1));
        dinv[g] = d;
        float4 xv = ((const float4*)x)[g];
        float4 o; o.x = d * xv.x; o.y = d * xv.y; o.z = d * xv.z; o.w = d * xv.w;
        ((float4*)xs)[g] = o;
    }
}

// ---- layer-1 aggregation: LDS push, one block per bucket -------------------
__global__ void k_aggL1(const unsigned int* __restrict__ bbuf, const int* __restrict__ histS,
                        const float* __restrict__ x, const float* __restrict__ xs,
                        const float* __restrict__ dinv, float* __restrict__ agg) {
    __shared__ float facc[BNODE * 4];
    int t = threadIdx.x;  // 256
    int b = blockIdx.x;
    for (int i = t; i < BNODE * 4; i += 256) facc[i] = 0.f;
    int base = histS[b * GE2];
    int next = (b == NBUK - 1) ? NE : histS[(b + 1) * GE2];
    __syncthreads();
    for (int e = base + t; e < next; e += 256) {
        unsigned int u = bbuf[e];
        int s  = u & SRCMASK;
        int dl = u >> SRCBITS;
        float4 v = ((const float4*)xs)[s];
        atomicAdd(&facc[dl * 4 + 0], v.x);
        atomicAdd(&facc[dl * 4 + 1], v.y);
        atomicAdd(&facc[dl * 4 + 2], v.z);
        atomicAdd(&facc[dl * 4 + 3], v.w);
    }
    __syncthreads();
    int g = b * BNODE + t;
    if (t < BNODE && g < NN) {
        float d = dinv[g];
        float4 xi = ((const float4*)x)[g];
        float4 o;
        o.x = d * (facc[t * 4 + 0] + d * xi.x);
        o.y = d * (facc[t * 4 + 1] + d * xi.y);
        o.z = d * (facc[t * 4 + 2] + d * xi.z);
        o.w = d * (facc[t * 4 + 3] + d * xi.w);
        ((float4*)agg)[g] = o;
    }
}

// ---- h1 = relu(agg@W1 + b1); hs = bf16(dinv * (h1@W2)). 4 nodes/block ------
__global__ void k_mm(const float* __restrict__ agg, const float* __restrict__ W1,
                     const float* __restrict__ b1, const float* __restrict__ W2,
                     const float* __restrict__ dinv, unsigned short* __restrict__ hs) {
    __shared__ float sW2[64 * 64];
    __shared__ float sh1[4][64];
    int t = threadIdx.x;
#pragma unroll
    for (int r = 0; r < 16; ++r) sW2[r * 256 + t] = W2[r * 256 + t];
    int node = blockIdx.x * 4 + (t >> 6);
    int c = t & 63;
    float4 a = ((const float4*)agg)[node];
    float h = a.x * W1[c] + a.y * W1[64 + c] + a.z * W1[128 + c] + a.w * W1[192 + c];
    h = fmaxf(h + b1[c], 0.0f);
    sh1[t >> 6][c] = h;
    __syncthreads();
    const float* h1 = sh1[t >> 6];
    float sum = 0.0f;
#pragma unroll
    for (int k = 0; k < 64; ++k) sum = fmaf(h1[k], sW2[k * 64 + c], sum);
    hs[node * 64 + c] = f2bf(sum * dinv[node]);
}

// ---- layer-2 aggregation + head: LDS push, one block per bucket ------------
// Each half-wave handles one edge per sub-step; lane covers 2 bf16 cols.
__global__ void k_aggL2(const unsigned int* __restrict__ bbuf, const int* __restrict__ histS,
                        const unsigned short* __restrict__ hs, const float* __restrict__ dinv,
                        const float* __restrict__ b2, const float* __restrict__ Wl,
                        const float* __restrict__ bl, float* __restrict__ out) {
    __shared__ float acc[BNODE * APAD];
    int t = threadIdx.x;  // 256 = 4 waves
    int b = blockIdx.x;
    for (int i = t; i < BNODE * APAD; i += 256) acc[i] = 0.f;
    int base = histS[b * GE2];
    int next = (b == NBUK - 1) ? NE : histS[(b + 1) * GE2];
    int sz = next - base;
    const unsigned int* buf = bbuf + base;
    __syncthreads();
    int wave = t >> 6, half = (t >> 5) & 1, lp = t & 31;
    int lane2 = lp * 2;
    int nIter = (sz + 31) >> 5;     // 32 edges per block-iter (4 waves x 8)
    for (int it = 0; it < nIter; ++it) {
        int e = it * 32 + wave * 8 + half;   // this half-wave: e, e+2, e+4, e+6
        bool p0 = (e < sz), p1 = (e + 2 < sz), p2 = (e + 4 < sz), p3 = (e + 6 < sz);
        unsigned int u0 = p0 ? buf[e]     : 0u;
        unsigned int u1 = p1 ? buf[e + 2] : 0u;
        unsigned int u2 = p2 ? buf[e + 4] : 0u;
        unsigned int u3 = p3 ? buf[e + 6] : 0u;
        unsigned int w0 = p0 ? *(const unsigned int*)(hs + (u0 & SRCMASK) * 64 + lane2) : 0u;
        unsigned int w1 = p1 ? *(const unsigned int*)(hs + (u1 & SRCMASK) * 64 + lane2) : 0u;
        unsigned int w2 = p2 ? *(const unsigned int*)(hs + (u2 & SRCMASK) * 64 + lane2) : 0u;
        unsigned int w3 = p3 ? *(const unsigned int*)(hs + (u3 & SRCMASK) * 64 + lane2) : 0u;
        if (p0) { int r = (int)(u0 >> SRCBITS) * APAD + lane2;
                  atomicAdd(&acc[r],     __uint_as_float(w0 << 16));
                  atomicAdd(&acc[r + 1], __uint_as_float(w0 & 0xFFFF0000u)); }
        if (p1) { int r = (int)(u1 >> SRCBITS) * APAD + lane2;
                  atomicAdd(&acc[r],     __uint_as_float(w1 << 16));
                  atomicAdd(&acc[r + 1], __uint_as_float(w1 & 0xFFFF0000u)); }
        if (p2) { int r = (int)(u2 >> SRCBITS) * APAD + lane2;
                  atomicAdd(&acc[r],     __uint_as_float(w2 << 16));
                  atomicAdd(&acc[r + 1], __uint_as_float(w2 & 0xFFFF0000u)); }
        if (p3) { int r = (int)(u3 >> SRCBITS) * APAD + lane2;
                  atomicAdd(&acc[r],     __uint_as_float(w3 << 16));
                  atomicAdd(&acc[r + 1], __uint_as_float(w3 & 0xFFFF0000u)); }
    }
    __syncthreads();
    // head epilogue: wave-per-node, 32 nodes per wave
    int c = t & 63;
    for (int k = 0; k < 32; ++k) {
        int nd = wave * 32 + k;
        int g = b * BNODE + nd;
        if (g < NN) {
            float a = acc[nd * APAD + c] + bf2f(hs[g * 64 + c]);  // + self loop
            float h2 = fmaxf(fmaf(dinv[g], a, b2[c]), 0.0f);
            float v = h2 * Wl[c];
#pragma unroll
            for (int off = 32; off; off >>= 1) v += __shfl_down(v, off, 64);
            if (c == 0) out[g] = v + bl[0];
        }
    }
}

extern "C" void kernel_launch(void* const* d_in, const int* in_sizes, int n_in,
                              void* d_out, int out_size, void* d_ws, size_t ws_size,
                              hipStream_t stream) {
    const float* x  = (const float*)d_in[0];
    const int*   ei = (const int*)d_in[1];
    const float* W1 = (const float*)d_in[2];
    const float* b1 = (const float*)d_in[3];
    const float* W2 = (const float*)d_in[4];
    const float* b2 = (const float*)d_in[5];
    const float* Wl = (const float*)d_in[6];
    const float* bl = (const float*)d_in[7];
    float* out = (float*)d_out;

    char* w = (char*)d_ws;
    float* dinv  = (float*)w;                  w += NN * 4;                          // 0.4 MB
    float* xs    = (float*)w;                  w += (size_t)NN * 4 * 4;              // 1.6 MB
    float* agg   = (float*)w;                  w += (size_t)NN * 4 * 4;              // 1.6 MB
    unsigned short* hs = (unsigned short*)w;   w += (size_t)NN * HID * 2;            // 12.8 MB
    int*   histG = (int*)w;                    w += (size_t)SCANN * 4;               // 2.45 MB
    int*   bsum  = (int*)w;                    w += 1024 * 4;
    unsigned int* bbuf = (unsigned int*)w;     w += (size_t)NE * 4;                  // 6.4 MB
    int*   flag  = (int*)w;                    w += 4;    // ~25.3 MB total

    hipLaunchKernelGGL(k_detect, dim3(1),    dim3(64),   0, stream, ei, flag);
    hipLaunchKernelGGL(k_histA,  dim3(GE2),  dim3(256),  0, stream, ei, flag, histG);
    hipLaunchKernelGGL(k_scan1,  dim3(NCH),  dim3(256),  0, stream, histG, bsum);
    hipLaunchKernelGGL(k_scan2,  dim3(1),    dim3(1024), 0, stream, bsum);
    hipLaunchKernelGGL(k_scan3,  dim3(NCH),  dim3(256),  0, stream, histG, bsum);
    hipLaunchKernelGGL(k_fillA,  dim3(GE2),  dim3(256),  0, stream, ei, flag, histG, bbuf);
    hipLaunchKernelGGL(k_cntB,   dim3(NBUK), dim3(256),  0, stream, bbuf, histG, x, dinv, xs);
    hipLaunchKernelGGL(k_aggL1,  dim3(NBUK), dim3(256),  0, stream, bbuf, histG, x, xs, dinv, agg);
    hipLaunchKernelGGL(k_mm,     dim3(NN/4), dim3(256),  0, stream, agg, W1, b1, W2, dinv, hs);
    hipLaunchKernelGGL(k_aggL2,  dim3(NBUK), dim3(256),  0, stream,
                       bbuf, histG, hs, dinv, b2, Wl, bl, out);
}

// Round 10
// 231.400 us; speedup vs baseline: 3.9218x; 3.9218x over previous
//
#include <hip/hip_runtime.h>

#define NN 100000
#define NE 1600000
#define HID 64
#define NBUK 391              // buckets of 256 node ids: (NN+255)/256
#define SRCBITS 17
#define SRCMASK 0x1FFFF
#define EBLK 2048             // edges per histogram/fill block
#define GE2 ((NE + EBLK - 1) / EBLK)        // 782 edge-blocks
#define SCANN (NBUK * GE2)    // 305,762
#define CHUNK 1024
#define NCH ((SCANN + CHUNK - 1) / CHUNK)   // 299 chunks

__device__ __forceinline__ float bf2f(unsigned short u) {
    return __uint_as_float(((unsigned int)u) << 16);
}
__device__ __forceinline__ unsigned short f2bf(float f) {   // RTNE
    unsigned int x = __float_as_uint(f);
    return (unsigned short)((x + 0x7FFFu + ((x >> 16) & 1u)) >> 16);
}

__device__ __forceinline__ int ld_idx(const int* __restrict__ ei, int off, int is64) {
    return is64 ? ei[2 * off] : ei[off];
}

// int64 edges have all-zero odd int32 words (values < 2^31). Wave-0 ballot.
__device__ __forceinline__ int detect_flag(const int* __restrict__ ei, int t, int* sflag) {
    if (t < 64) {
        unsigned long long b = __ballot(ei[2 * t + 1] != 0);
        if (t == 0) *sflag = (b == 0ULL) ? 1 : 0;  // 1 => int64 layout
    }
    __syncthreads();
    return *sflag;
}

// ---- pass A1: per-block bucket histogram (LDS atomics only) ----------------
__global__ void k_histA(const int* __restrict__ ei, int* __restrict__ histG) {
    __shared__ int hist[NBUK];
    __shared__ int sflag;
    int t = threadIdx.x;  // 256
    for (int i = t; i < NBUK; i += 256) hist[i] = 0;
    int f = detect_flag(ei, t, &sflag);   // includes __syncthreads
    int base = blockIdx.x * EBLK;
#pragma unroll
    for (int k = 0; k < EBLK / 256; ++k) {
        int e = base + k * 256 + t;
        if (e < NE) {
            int d = ld_idx(ei, NE + e, f);
            atomicAdd(&hist[d >> 8], 1);
        }
    }
    __syncthreads();
    for (int i = t; i < NBUK; i += 256) histG[i * GE2 + blockIdx.x] = hist[i];
}

// ---- 3-stage exclusive scan of SCANN counts --------------------------------
__global__ void k_scan1(int* __restrict__ g, int* __restrict__ bsum) {
    __shared__ int s[256];
    int t = threadIdx.x;
    int i4 = blockIdx.x * 256 + t;
    int base = i4 * 4;
    int4 v = make_int4(0, 0, 0, 0);
    if (base + 3 < SCANN) v = ((const int4*)g)[i4];
    else {
        if (base + 0 < SCANN) v.x = g[base + 0];
        if (base + 1 < SCANN) v.y = g[base + 1];
        if (base + 2 < SCANN) v.z = g[base + 2];
        if (base + 3 < SCANN) v.w = g[base + 3];
    }
    int tsum = v.x + v.y + v.z + v.w;
    s[t] = tsum; __syncthreads();
    for (int off = 1; off < 256; off <<= 1) {
        int u = (t >= off) ? s[t - off] : 0;
        __syncthreads();
        s[t] += u;
        __syncthreads();
    }
    int run = s[t] - tsum;
    int4 o;
    o.x = run; run += v.x;
    o.y = run; run += v.y;
    o.z = run; run += v.z;
    o.w = run;
    if (base + 3 < SCANN) ((int4*)g)[i4] = o;
    else {
        if (base + 0 < SCANN) g[base + 0] = o.x;
        if (base + 1 < SCANN) g[base + 1] = o.y;
        if (base + 2 < SCANN) g[base + 2] = o.z;
        if (base + 3 < SCANN) g[base + 3] = o.w;
    }
    if (t == 255) bsum[blockIdx.x] = s[255];
}

__global__ void k_scan2(int* __restrict__ bsum) {
    __shared__ int s[512];
    int t = threadIdx.x;  // 512
    int v = (t < NCH) ? bsum[t] : 0;
    s[t] = v; __syncthreads();
    for (int off = 1; off < 512; off <<= 1) {
        int u = (t >= off) ? s[t - off] : 0;
        __syncthreads();
        s[t] += u;
        __syncthreads();
    }
    if (t < NCH) bsum[t] = s[t] - v;
}

__global__ void k_scan3(int* __restrict__ g, const int* __restrict__ bsum) {
    int t = threadIdx.x;
    int i4 = blockIdx.x * 256 + t;
    int base = i4 * 4;
    int add = bsum[blockIdx.x];
    if (base + 3 < SCANN) {
        int4 v = ((const int4*)g)[i4];
        v.x += add; v.y += add; v.z += add; v.w += add;
        ((int4*)g)[i4] = v;
    } else {
        if (base + 0 < SCANN) g[base + 0] += add;
        if (base + 1 < SCANN) g[base + 1] += add;
        if (base + 2 < SCANN) g[base + 2] += add;
        if (base + 3 < SCANN) g[base + 3] += add;
    }
}

// ---- pass A2: place packed edges into disjoint per-(block,bucket) ranges ---
__global__ void k_fillA(const int* __restrict__ ei, const int* __restrict__ histS,
                        unsigned int* __restrict__ bbuf) {
    __shared__ int cur[NBUK];
    __shared__ int sflag;
    int t = threadIdx.x;  // 256
    for (int i = t; i < NBUK; i += 256) cur[i] = histS[i * GE2 + blockIdx.x];
    int f = detect_flag(ei, t, &sflag);   // includes __syncthreads
    int base = blockIdx.x * EBLK;
#pragma unroll
    for (int k = 0; k < EBLK / 256; ++k) {
        int e = base + k * 256 + t;
        if (e < NE) {
            int s = ld_idx(ei, e, f);
            int d = ld_idx(ei, NE + e, f);
            int p = atomicAdd(&cur[d >> 8], 1);   // LDS atomic
            bbuf[p] = ((unsigned int)(d & 255) << SRCBITS) | (unsigned int)s;
        }
    }
}

// ---- pass B: per-bucket 256-slot sort -> cnt/offs/dinv/xs + csr ------------
__global__ void k_passB(const unsigned int* __restrict__ bbuf, const int* __restrict__ histS,
                        const float* __restrict__ x,
                        int* __restrict__ cnt, int* __restrict__ offs,
                        float* __restrict__ dinv, float* __restrict__ xs,
                        int* __restrict__ csr) {
    __shared__ int hist[256];
    __shared__ int scn[256];
    __shared__ int cur[256];
    int t = threadIdx.x;  // 256
    int b = blockIdx.x;
    int base = histS[b * GE2];
    int next = (b == NBUK - 1) ? NE : histS[(b + 1) * GE2];
    int sz = next - base;
    const unsigned int* buf = bbuf + base;
    hist[t] = 0;
    __syncthreads();
    for (int e = t; e < sz; e += 256)
        atomicAdd(&hist[buf[e] >> SRCBITS], 1);
    __syncthreads();
    int deg = hist[t];
    scn[t] = deg; __syncthreads();
    for (int off = 1; off < 256; off <<= 1) {
        int u = (t >= off) ? scn[t - off] : 0;
        __syncthreads();
        scn[t] += u;
        __syncthreads();
    }
    int myoff = base + scn[t] - deg;
    int node = b * 256 + t;
    if (node < NN) {
        cnt[node]  = deg;
        offs[node] = myoff;
        float d = 1.0f / sqrtf((float)(deg + 1));
        dinv[node] = d;
        float4 xv = ((const float4*)x)[node];
        float4 o; o.x = d * xv.x; o.y = d * xv.y; o.z = d * xv.z; o.w = d * xv.w;
        ((float4*)xs)[node] = o;
    }
    cur[t] = myoff;
    __syncthreads();
    for (int e = t; e < sz; e += 256) {
        unsigned int u = buf[e];
        int p = atomicAdd(&cur[u >> SRCBITS], 1);
        csr[p] = (int)(u & SRCMASK);
    }
}

// ---- layer-1 aggregation, 8-way ILP ----------------------------------------
__global__ void k_agg1(const float* __restrict__ x, const float* __restrict__ xs,
                       const float* __restrict__ dinv, const int* __restrict__ offs,
                       const int* __restrict__ cnt, const int* __restrict__ csr,
                       float* __restrict__ agg) {
    int i = blockIdx.x * 256 + threadIdx.x;
    if (i >= NN) return;
    float sx = 0.f, sy = 0.f, sz = 0.f, sw = 0.f;
    int b = offs[i], n = cnt[i];
    int j = 0;
    for (; j + 8 <= n; j += 8) {
        int s0 = csr[b + j + 0], s1 = csr[b + j + 1], s2 = csr[b + j + 2], s3 = csr[b + j + 3];
        int s4 = csr[b + j + 4], s5 = csr[b + j + 5], s6 = csr[b + j + 6], s7 = csr[b + j + 7];
        float4 v0 = ((const float4*)xs)[s0];
        float4 v1 = ((const float4*)xs)[s1];
        float4 v2 = ((const float4*)xs)[s2];
        float4 v3 = ((const float4*)xs)[s3];
        float4 v4 = ((const float4*)xs)[s4];
        float4 v5 = ((const float4*)xs)[s5];
        float4 v6 = ((const float4*)xs)[s6];
        float4 v7 = ((const float4*)xs)[s7];
        sx += v0.x + v1.x + v2.x + v3.x + v4.x + v5.x + v6.x + v7.x;
        sy += v0.y + v1.y + v2.y + v3.y + v4.y + v5.y + v6.y + v7.y;
        sz += v0.z + v1.z + v2.z + v3.z + v4.z + v5.z + v6.z + v7.z;
        sw += v0.w + v1.w + v2.w + v3.w + v4.w + v5.w + v6.w + v7.w;
    }
    for (; j < n; ++j) {
        int s = csr[b + j];
        float4 v = ((const float4*)xs)[s];
        sx += v.x; sy += v.y; sz += v.z; sw += v.w;
    }
    float d = dinv[i];
    float4 xi = ((const float4*)x)[i];
    float4 o;
    o.x = d * (sx + d * xi.x);
    o.y = d * (sy + d * xi.y);
    o.z = d * (sz + d * xi.z);
    o.w = d * (sw + d * xi.w);
    ((float4*)agg)[i] = o;
}

// ---- h1 = relu(agg@W1 + b1); hs = bf16(dinv * (h1@W2)). 4 nodes/block ------
__global__ void k_mm(const float* __restrict__ agg, const float* __restrict__ W1,
                     const float* __restrict__ b1, const float* __restrict__ W2,
                     const float* __restrict__ dinv, unsigned short* __restrict__ hs) {
    __shared__ float sW2[64 * 64];
    __shared__ float sh1[4][64];
    int t = threadIdx.x;
#pragma unroll
    for (int r = 0; r < 16; ++r) sW2[r * 256 + t] = W2[r * 256 + t];
    int node = blockIdx.x * 4 + (t >> 6);
    int c = t & 63;
    float4 a = ((const float4*)agg)[node];
    float h = a.x * W1[c] + a.y * W1[64 + c] + a.z * W1[128 + c] + a.w * W1[192 + c];
    h = fmaxf(h + b1[c], 0.0f);
    sh1[t >> 6][c] = h;
    __syncthreads();
    const float* h1 = sh1[t >> 6];
    float sum = 0.0f;
#pragma unroll
    for (int k = 0; k < 64; ++k) sum = fmaf(h1[k], sW2[k * 64 + c], sum);
    hs[node * 64 + c] = f2bf(sum * dinv[node]);
}

// ---- layer-2 gather + head, fused, 16-way ILP, bf16 hs. One wave per node. -
__global__ void k_gather_head(const unsigned short* __restrict__ hs, const int* __restrict__ offs,
                              const int* __restrict__ cnt, const int* __restrict__ csr,
                              const float* __restrict__ dinv, const float* __restrict__ b2,
                              const float* __restrict__ Wl, const float* __restrict__ bl,
                              float* __restrict__ out) {
    int t = threadIdx.x;
    int node = blockIdx.x * 4 + (t >> 6);
    int c = t & 63;
    int b = offs[node], n = cnt[node];
    const unsigned short* hc = hs + c;
    float a = bf2f(hc[node * 64]);               // self loop (hs already *dinv[self])
    int myidx = (c < n) ? csr[b + c] : 0;        // prefetch up to 64 indices
    int m = n < 64 ? n : 64;
    int j = 0;
    float a0 = 0.f, a1 = 0.f, a2 = 0.f, a3 = 0.f;
    float a4 = 0.f, a5 = 0.f, a6 = 0.f, a7 = 0.f;
    float a8 = 0.f, a9 = 0.f, aA = 0.f, aB = 0.f;
    float aC = 0.f, aD = 0.f, aE = 0.f, aF = 0.f;
    for (; j + 16 <= m; j += 16) {               // 16 loads in flight
        int s0 = __shfl(myidx, j + 0, 64),  s1 = __shfl(myidx, j + 1, 64);
        int s2 = __shfl(myidx, j + 2, 64),  s3 = __shfl(myidx, j + 3, 64);
        int s4 = __shfl(myidx, j + 4, 64),  s5 = __shfl(myidx, j + 5, 64);
        int s6 = __shfl(myidx, j + 6, 64),  s7 = __shfl(myidx, j + 7, 64);
        int s8 = __shfl(myidx, j + 8, 64),  s9 = __shfl(myidx, j + 9, 64);
        int sA = __shfl(myidx, j + 10, 64), sB = __shfl(myidx, j + 11, 64);
        int sC = __shfl(myidx, j + 12, 64), sD = __shfl(myidx, j + 13, 64);
        int sE = __shfl(myidx, j + 14, 64), sF = __shfl(myidx, j + 15, 64);
        unsigned short v0 = hc[s0 * 64], v1 = hc[s1 * 64], v2 = hc[s2 * 64], v3 = hc[s3 * 64];
        unsigned short v4 = hc[s4 * 64], v5 = hc[s5 * 64], v6 = hc[s6 * 64], v7 = hc[s7 * 64];
        unsigned short v8 = hc[s8 * 64], v9 = hc[s9 * 64], vA = hc[sA * 64], vB = hc[sB * 64];
        unsigned short vC = hc[sC * 64], vD = hc[sD * 64], vE = hc[sE * 64], vF = hc[sF * 64];
        a0 += bf2f(v0); a1 += bf2f(v1); a2 += bf2f(v2); a3 += bf2f(v3);
        a4 += bf2f(v4); a5 += bf2f(v5); a6 += bf2f(v6); a7 += bf2f(v7);
        a8 += bf2f(v8); a9 += bf2f(v9); aA += bf2f(vA); aB += bf2f(vB);
        aC += bf2f(vC); aD += bf2f(vD); aE += bf2f(vE); aF += bf2f(vF);
    }
    for (; j + 4 <= m; j += 4) {
        int s0 = __shfl(myidx, j + 0, 64), s1 = __shfl(myidx, j + 1, 64);
        int s2 = __shfl(myidx, j + 2, 64), s3 = __shfl(myidx, j + 3, 64);
        unsigned short v0 = hc[s0 * 64], v1 = hc[s1 * 64];
        unsigned short v2 = hc[s2 * 64], v3 = hc[s3 * 64];
        a0 += bf2f(v0); a1 += bf2f(v1); a2 += bf2f(v2); a3 += bf2f(v3);
    }
    for (; j < m; ++j) {
        int s = __shfl(myidx, j, 64);
        a += bf2f(hc[s * 64]);
    }
    for (j = 64; j < n; ++j) {                   // rare: deg > 64
        int s = csr[b + j];
        a += bf2f(hc[s * 64]);
    }
    a += (((a0 + a1) + (a2 + a3)) + ((a4 + a5) + (a6 + a7)))
       + (((a8 + a9) + (aA + aB)) + ((aC + aD) + (aE + aF)));
    float h2 = fmaxf(fmaf(dinv[node], a, b2[c]), 0.0f);
    float v = h2 * Wl[c];
#pragma unroll
    for (int off = 32; off; off >>= 1) v += __shfl_down(v, off, 64);
    if (c == 0) out[node] = v + bl[0];
}

extern "C" void kernel_launch(void* const* d_in, const int* in_sizes, int n_in,
                              void* d_out, int out_size, void* d_ws, size_t ws_size,
                              hipStream_t stream) {
    const float* x  = (const float*)d_in[0];
    const int*   ei = (const int*)d_in[1];
    const float* W1 = (const float*)d_in[2];
    const float* b1 = (const float*)d_in[3];
    const float* W2 = (const float*)d_in[4];
    const float* b2 = (const float*)d_in[5];
    const float* Wl = (const float*)d_in[6];
    const float* bl = (const float*)d_in[7];
    float* out = (float*)d_out;

    char* w = (char*)d_ws;
    float* dinv  = (float*)w;                  w += NN * 4;
    int*   cnt   = (int*)w;                    w += NN * 4;
    int*   offs  = (int*)w;                    w += NN * 4;
    int*   csr   = (int*)w;                    w += NE * 4;
    float* xs    = (float*)w;                  w += NN * 4 * 4;
    float* agg   = (float*)w;                  w += NN * 4 * 4;
    unsigned short* hs = (unsigned short*)w;   w += (size_t)NN * HID * 2;           // 12.8 MB
    int*   histG = (int*)w;                    w += (size_t)((SCANN + 3) & ~3) * 4; // 1.22 MB
    int*   bsum  = (int*)w;                    w += 512 * 4;
    unsigned int* bbuf = (unsigned int*)w;     w += (size_t)NE * 4;                 // 6.4 MB

    const int GN = (NN + 255) / 256;       // 391

    hipLaunchKernelGGL(k_histA,  dim3(GE2),  dim3(256), 0, stream, ei, histG);
    hipLaunchKernelGGL(k_scan1,  dim3(NCH),  dim3(256), 0, stream, histG, bsum);
    hipLaunchKernelGGL(k_scan2,  dim3(1),    dim3(512), 0, stream, bsum);
    hipLaunchKernelGGL(k_scan3,  dim3(NCH),  dim3(256), 0, stream, histG, bsum);
    hipLaunchKernelGGL(k_fillA,  dim3(GE2),  dim3(256), 0, stream, ei, histG, bbuf);
    hipLaunchKernelGGL(k_passB,  dim3(NBUK), dim3(256), 0, stream,
                       bbuf, histG, x, cnt, offs, dinv, xs, csr);

    hipLaunchKernelGGL(k_agg1, dim3(GN), dim3(256), 0, stream,
                       x, xs, dinv, offs, cnt, csr, agg);
    hipLaunchKernelGGL(k_mm, dim3(NN / 4), dim3(256), 0, stream,
                       agg, W1, b1, W2, dinv, hs);
    hipLaunchKernelGGL(k_gather_head, dim3(NN / 4), dim3(256), 0, stream,
                       hs, offs, cnt, csr, dinv, b2, Wl, bl, out);
}

// Round 11
// 217.455 us; speedup vs baseline: 4.1733x; 1.0641x over previous
//
#include <hip/hip_runtime.h>

#define NN 100000
#define NE 1600000
#define HID 64
#define NBUK 391              // buckets of 256 node ids: (NN+255)/256
#define SRCBITS 17
#define SRCMASK 0x1FFFF
#define EBLK 2048             // edges per histogram/fill block
#define GE2 ((NE + EBLK - 1) / EBLK)        // 782 edge-blocks
#define SCANN (NBUK * GE2)    // 305,762
#define CHUNK 1024
#define NCH ((SCANN + CHUNK - 1) / CHUNK)   // 299 chunks

__device__ __forceinline__ float bf2f(unsigned short u) {
    return __uint_as_float(((unsigned int)u) << 16);
}
__device__ __forceinline__ unsigned short f2bf(float f) {   // RTNE
    unsigned int x = __float_as_uint(f);
    return (unsigned short)((x + 0x7FFFu + ((x >> 16) & 1u)) >> 16);
}
__device__ __forceinline__ float bflo(unsigned int u) { return __uint_as_float(u << 16); }
__device__ __forceinline__ float bfhi(unsigned int u) { return __uint_as_float(u & 0xFFFF0000u); }

__device__ __forceinline__ int ld_idx(const int* __restrict__ ei, int off, int is64) {
    return is64 ? ei[2 * off] : ei[off];
}

// int64 edges have all-zero odd int32 words (values < 2^31). Wave-0 ballot.
__device__ __forceinline__ int detect_flag(const int* __restrict__ ei, int t, int* sflag) {
    if (t < 64) {
        unsigned long long b = __ballot(ei[2 * t + 1] != 0);
        if (t == 0) *sflag = (b == 0ULL) ? 1 : 0;  // 1 => int64 layout
    }
    __syncthreads();
    return *sflag;
}

// ---- pass A1: per-block bucket histogram (LDS atomics only) ----------------
__global__ void k_histA(const int* __restrict__ ei, int* __restrict__ histG) {
    __shared__ int hist[NBUK];
    __shared__ int sflag;
    int t = threadIdx.x;  // 256
    for (int i = t; i < NBUK; i += 256) hist[i] = 0;
    int f = detect_flag(ei, t, &sflag);   // includes __syncthreads
    int base = blockIdx.x * EBLK;
#pragma unroll
    for (int k = 0; k < EBLK / 256; ++k) {
        int e = base + k * 256 + t;
        if (e < NE) {
            int d = ld_idx(ei, NE + e, f);
            atomicAdd(&hist[d >> 8], 1);
        }
    }
    __syncthreads();
    for (int i = t; i < NBUK; i += 256) histG[i * GE2 + blockIdx.x] = hist[i];
}

// ---- 3-stage exclusive scan of SCANN counts --------------------------------
__global__ void k_scan1(int* __restrict__ g, int* __restrict__ bsum) {
    __shared__ int s[256];
    int t = threadIdx.x;
    int i4 = blockIdx.x * 256 + t;
    int base = i4 * 4;
    int4 v = make_int4(0, 0, 0, 0);
    if (base + 3 < SCANN) v = ((const int4*)g)[i4];
    else {
        if (base + 0 < SCANN) v.x = g[base + 0];
        if (base + 1 < SCANN) v.y = g[base + 1];
        if (base + 2 < SCANN) v.z = g[base + 2];
        if (base + 3 < SCANN) v.w = g[base + 3];
    }
    int tsum = v.x + v.y + v.z + v.w;
    s[t] = tsum; __syncthreads();
    for (int off = 1; off < 256; off <<= 1) {
        int u = (t >= off) ? s[t - off] : 0;
        __syncthreads();
        s[t] += u;
        __syncthreads();
    }
    int run = s[t] - tsum;
    int4 o;
    o.x = run; run += v.x;
    o.y = run; run += v.y;
    o.z = run; run += v.z;
    o.w = run;
    if (base + 3 < SCANN) ((int4*)g)[i4] = o;
    else {
        if (base + 0 < SCANN) g[base + 0] = o.x;
        if (base + 1 < SCANN) g[base + 1] = o.y;
        if (base + 2 < SCANN) g[base + 2] = o.z;
        if (base + 3 < SCANN) g[base + 3] = o.w;
    }
    if (t == 255) bsum[blockIdx.x] = s[255];
}

__global__ void k_scan2(int* __restrict__ bsum) {
    __shared__ int s[512];
    int t = threadIdx.x;  // 512
    int v = (t < NCH) ? bsum[t] : 0;
    s[t] = v; __syncthreads();
    for (int off = 1; off < 512; off <<= 1) {
        int u = (t >= off) ? s[t - off] : 0;
        __syncthreads();
        s[t] += u;
        __syncthreads();
    }
    if (t < NCH) bsum[t] = s[t] - v;
}

__global__ void k_scan3(int* __restrict__ g, const int* __restrict__ bsum) {
    int t = threadIdx.x;
    int i4 = blockIdx.x * 256 + t;
    int base = i4 * 4;
    int add = bsum[blockIdx.x];
    if (base + 3 < SCANN) {
        int4 v = ((const int4*)g)[i4];
        v.x += add; v.y += add; v.z += add; v.w += add;
        ((int4*)g)[i4] = v;
    } else {
        if (base + 0 < SCANN) g[base + 0] += add;
        if (base + 1 < SCANN) g[base + 1] += add;
        if (base + 2 < SCANN) g[base + 2] += add;
        if (base + 3 < SCANN) g[base + 3] += add;
    }
}

// ---- pass A2: place packed edges into disjoint per-(block,bucket) ranges ---
__global__ void k_fillA(const int* __restrict__ ei, const int* __restrict__ histS,
                        unsigned int* __restrict__ bbuf) {
    __shared__ int cur[NBUK];
    __shared__ int sflag;
    int t = threadIdx.x;  // 256
    for (int i = t; i < NBUK; i += 256) cur[i] = histS[i * GE2 + blockIdx.x];
    int f = detect_flag(ei, t, &sflag);   // includes __syncthreads
    int base = blockIdx.x * EBLK;
#pragma unroll
    for (int k = 0; k < EBLK / 256; ++k) {
        int e = base + k * 256 + t;
        if (e < NE) {
            int s = ld_idx(ei, e, f);
            int d = ld_idx(ei, NE + e, f);
            int p = atomicAdd(&cur[d >> 8], 1);   // LDS atomic
            bbuf[p] = ((unsigned int)(d & 255) << SRCBITS) | (unsigned int)s;
        }
    }
}

// ---- pass B: per-bucket 256-slot sort -> cnt/offs/dinv/xs + csr ------------
__global__ void k_passB(const unsigned int* __restrict__ bbuf, const int* __restrict__ histS,
                        const float* __restrict__ x,
                        int* __restrict__ cnt, int* __restrict__ offs,
                        float* __restrict__ dinv, float* __restrict__ xs,
                        int* __restrict__ csr) {
    __shared__ int hist[256];
    __shared__ int scn[256];
    __shared__ int cur[256];
    int t = threadIdx.x;  // 256
    int b = blockIdx.x;
    int base = histS[b * GE2];
    int next = (b == NBUK - 1) ? NE : histS[(b + 1) * GE2];
    int sz = next - base;
    const unsigned int* buf = bbuf + base;
    hist[t] = 0;
    __syncthreads();
    for (int e = t; e < sz; e += 256)
        atomicAdd(&hist[buf[e] >> SRCBITS], 1);
    __syncthreads();
    int deg = hist[t];
    scn[t] = deg; __syncthreads();
    for (int off = 1; off < 256; off <<= 1) {
        int u = (t >= off) ? scn[t - off] : 0;
        __syncthreads();
        scn[t] += u;
        __syncthreads();
    }
    int myoff = base + scn[t] - deg;
    int node = b * 256 + t;
    if (node < NN) {
        cnt[node]  = deg;
        offs[node] = myoff;
        float d = 1.0f / sqrtf((float)(deg + 1));
        dinv[node] = d;
        float4 xv = ((const float4*)x)[node];
        float4 o; o.x = d * xv.x; o.y = d * xv.y; o.z = d * xv.z; o.w = d * xv.w;
        ((float4*)xs)[node] = o;
    }
    cur[t] = myoff;
    __syncthreads();
    for (int e = t; e < sz; e += 256) {
        unsigned int u = buf[e];
        int p = atomicAdd(&cur[u >> SRCBITS], 1);
        csr[p] = (int)(u & SRCMASK);
    }
}

// ---- layer-1 aggregation, 8-way ILP ----------------------------------------
__global__ void k_agg1(const float* __restrict__ x, const float* __restrict__ xs,
                       const float* __restrict__ dinv, const int* __restrict__ offs,
                       const int* __restrict__ cnt, const int* __restrict__ csr,
                       float* __restrict__ agg) {
    int i = blockIdx.x * 256 + threadIdx.x;
    if (i >= NN) return;
    float sx = 0.f, sy = 0.f, sz = 0.f, sw = 0.f;
    int b = offs[i], n = cnt[i];
    int j = 0;
    for (; j + 8 <= n; j += 8) {
        int s0 = csr[b + j + 0], s1 = csr[b + j + 1], s2 = csr[b + j + 2], s3 = csr[b + j + 3];
        int s4 = csr[b + j + 4], s5 = csr[b + j + 5], s6 = csr[b + j + 6], s7 = csr[b + j + 7];
        float4 v0 = ((const float4*)xs)[s0];
        float4 v1 = ((const float4*)xs)[s1];
        float4 v2 = ((const float4*)xs)[s2];
        float4 v3 = ((const float4*)xs)[s3];
        float4 v4 = ((const float4*)xs)[s4];
        float4 v5 = ((const float4*)xs)[s5];
        float4 v6 = ((const float4*)xs)[s6];
        float4 v7 = ((const float4*)xs)[s7];
        sx += v0.x + v1.x + v2.x + v3.x + v4.x + v5.x + v6.x + v7.x;
        sy += v0.y + v1.y + v2.y + v3.y + v4.y + v5.y + v6.y + v7.y;
        sz += v0.z + v1.z + v2.z + v3.z + v4.z + v5.z + v6.z + v7.z;
        sw += v0.w + v1.w + v2.w + v3.w + v4.w + v5.w + v6.w + v7.w;
    }
    for (; j < n; ++j) {
        int s = csr[b + j];
        float4 v = ((const float4*)xs)[s];
        sx += v.x; sy += v.y; sz += v.z; sw += v.w;
    }
    float d = dinv[i];
    float4 xi = ((const float4*)x)[i];
    float4 o;
    o.x = d * (sx + d * xi.x);
    o.y = d * (sy + d * xi.y);
    o.z = d * (sz + d * xi.z);
    o.w = d * (sw + d * xi.w);
    ((float4*)agg)[i] = o;
}

// ---- h1 = relu(agg@W1 + b1); hs = bf16(dinv * (h1@W2)). 4 nodes/block ------
// Node-0 wave also zeroes the sentinel row hs[NN] (used by gather for
// out-of-range edges -> adds 0.0, branchless).
__global__ void k_mm(const float* __restrict__ agg, const float* __restrict__ W1,
                     const float* __restrict__ b1, const float* __restrict__ W2,
                     const float* __restrict__ dinv, unsigned short* __restrict__ hs) {
    __shared__ float sW2[64 * 64];
    __shared__ float sh1[4][64];
    int t = threadIdx.x;
#pragma unroll
    for (int r = 0; r < 16; ++r) sW2[r * 256 + t] = W2[r * 256 + t];
    int node = blockIdx.x * 4 + (t >> 6);
    int c = t & 63;
    float4 a = ((const float4*)agg)[node];
    float h = a.x * W1[c] + a.y * W1[64 + c] + a.z * W1[128 + c] + a.w * W1[192 + c];
    h = fmaxf(h + b1[c], 0.0f);
    sh1[t >> 6][c] = h;
    if (node == 0) hs[NN * 64 + c] = 0;   // zero sentinel row
    __syncthreads();
    const float* h1 = sh1[t >> 6];
    float sum = 0.0f;
#pragma unroll
    for (int k = 0; k < 64; ++k) sum = fmaf(h1[k], sW2[k * 64 + c], sum);
    hs[node * 64 + c] = f2bf(sum * dinv[node]);
}

// ---- layer-2 gather + head, fused, quad-row loads. One wave per node. ------
// Lane c: group qg=c>>4 takes edges j+qg (mod 4); slot ql=c&15 covers cols
// 4ql..4ql+3 (uint2 = 4 bf16). One wave-load = 4 neighbor rows. Butterfly
// (xor 16/32) merges per-column partials; head reduces over width 16.
__global__ void k_gather_head(const unsigned short* __restrict__ hs, const int* __restrict__ offs,
                              const int* __restrict__ cnt, const int* __restrict__ csr,
                              const float* __restrict__ dinv, const float* __restrict__ b2,
                              const float* __restrict__ Wl, const float* __restrict__ bl,
                              float* __restrict__ out) {
    int t = threadIdx.x;
    int node = blockIdx.x * 4 + (t >> 6);
    int c = t & 63;
    int qg = c >> 4;
    int ql = c & 15;
    int b = offs[node], n = cnt[node];
    const uint2* hrow = (const uint2*)hs;        // 16 uint2 per row
    int myidx = (c < n) ? csr[b + c] : NN;       // NN = zero sentinel row
    int m = n < 64 ? n : 64;
    float4 A = make_float4(0.f, 0.f, 0.f, 0.f);
    float4 B = make_float4(0.f, 0.f, 0.f, 0.f);
    for (int j = 0; j < m; j += 16) {            // 16 edges per iter, 4 loads in flight
        int s0 = __shfl(myidx, j + qg, 64);
        int s1 = __shfl(myidx, j + 4 + qg, 64);
        int s2 = __shfl(myidx, j + 8 + qg, 64);
        int s3 = __shfl(myidx, j + 12 + qg, 64);
        uint2 u0 = hrow[s0 * 16 + ql];
        uint2 u1 = hrow[s1 * 16 + ql];
        uint2 u2 = hrow[s2 * 16 + ql];
        uint2 u3 = hrow[s3 * 16 + ql];
        A.x += bflo(u0.x); A.y += bfhi(u0.x); A.z += bflo(u0.y); A.w += bfhi(u0.y);
        B.x += bflo(u1.x); B.y += bfhi(u1.x); B.z += bflo(u1.y); B.w += bfhi(u1.y);
        A.x += bflo(u2.x); A.y += bfhi(u2.x); A.z += bflo(u2.y); A.w += bfhi(u2.y);
        B.x += bflo(u3.x); B.y += bfhi(u3.x); B.z += bflo(u3.y); B.w += bfhi(u3.y);
    }
    for (int j = 64; j < n; j += 4) {            // rare: deg > 64
        int e = j + qg;
        int s = (e < n) ? csr[b + e] : NN;
        uint2 u = hrow[s * 16 + ql];
        A.x += bflo(u.x); A.y += bfhi(u.x); A.z += bflo(u.y); A.w += bfhi(u.y);
    }
    float4 S;
    S.x = A.x + B.x; S.y = A.y + B.y; S.z = A.z + B.z; S.w = A.w + B.w;
    S.x += __shfl_xor(S.x, 16, 64); S.x += __shfl_xor(S.x, 32, 64);
    S.y += __shfl_xor(S.y, 16, 64); S.y += __shfl_xor(S.y, 32, 64);
    S.z += __shfl_xor(S.z, 16, 64); S.z += __shfl_xor(S.z, 32, 64);
    S.w += __shfl_xor(S.w, 16, 64); S.w += __shfl_xor(S.w, 32, 64);
    uint2 uS = hrow[node * 16 + ql];             // self loop, once
    S.x += bflo(uS.x); S.y += bfhi(uS.x); S.z += bflo(uS.y); S.w += bfhi(uS.y);
    float4 bv = ((const float4*)b2)[ql];
    float4 wv = ((const float4*)Wl)[ql];
    float dn = dinv[node];
    float v = fmaxf(fmaf(dn, S.x, bv.x), 0.f) * wv.x
            + fmaxf(fmaf(dn, S.y, bv.y), 0.f) * wv.y
            + fmaxf(fmaf(dn, S.z, bv.z), 0.f) * wv.z
            + fmaxf(fmaf(dn, S.w, bv.w), 0.f) * wv.w;
#pragma unroll
    for (int off = 8; off; off >>= 1) v += __shfl_down(v, off, 16);
    if (c == 0) out[node] = v + bl[0];
}

extern "C" void kernel_launch(void* const* d_in, const int* in_sizes, int n_in,
                              void* d_out, int out_size, void* d_ws, size_t ws_size,
                              hipStream_t stream) {
    const float* x  = (const float*)d_in[0];
    const int*   ei = (const int*)d_in[1];
    const float* W1 = (const float*)d_in[2];
    const float* b1 = (const float*)d_in[3];
    const float* W2 = (const float*)d_in[4];
    const float* b2 = (const float*)d_in[5];
    const float* Wl = (const float*)d_in[6];
    const float* bl = (const float*)d_in[7];
    float* out = (float*)d_out;

    char* w = (char*)d_ws;
    float* dinv  = (float*)w;                  w += NN * 4;
    int*   cnt   = (int*)w;                    w += NN * 4;
    int*   offs  = (int*)w;                    w += NN * 4;
    int*   csr   = (int*)w;                    w += NE * 4;
    float* xs    = (float*)w;                  w += NN * 4 * 4;
    float* agg   = (float*)w;                  w += NN * 4 * 4;
    unsigned short* hs = (unsigned short*)w;   w += (size_t)(NN + 1) * HID * 2;     // 12.8 MB (+sentinel)
    int*   histG = (int*)w;                    w += (size_t)((SCANN + 3) & ~3) * 4; // 1.22 MB
    int*   bsum  = (int*)w;                    w += 512 * 4;
    unsigned int* bbuf = (unsigned int*)w;     w += (size_t)NE * 4;                 // 6.4 MB

    const int GN = (NN + 255) / 256;       // 391

    hipLaunchKernelGGL(k_histA,  dim3(GE2),  dim3(256), 0, stream, ei, histG);
    hipLaunchKernelGGL(k_scan1,  dim3(NCH),  dim3(256), 0, stream, histG, bsum);
    hipLaunchKernelGGL(k_scan2,  dim3(1),    dim3(512), 0, stream, bsum);
    hipLaunchKernelGGL(k_scan3,  dim3(NCH),  dim3(256), 0, stream, histG, bsum);
    hipLaunchKernelGGL(k_fillA,  dim3(GE2),  dim3(256), 0, stream, ei, histG, bbuf);
    hipLaunchKernelGGL(k_passB,  dim3(NBUK), dim3(256), 0, stream,
                       bbuf, histG, x, cnt, offs, dinv, xs, csr);

    hipLaunchKernelGGL(k_agg1, dim3(GN), dim3(256), 0, stream,
                       x, xs, dinv, offs, cnt, csr, agg);
    hipLaunchKernelGGL(k_mm, dim3(NN / 4), dim3(256), 0, stream,
                       agg, W1, b1, W2, dinv, hs);
    hipLaunchKernelGGL(k_gather_head, dim3(NN / 4), dim3(256), 0, stream,
                       hs, offs, cnt, csr, dinv, b2, Wl, bl, out);
}

// Round 12
// 184.500 us; speedup vs baseline: 4.9188x; 1.1786x over previous
//
#include <hip/hip_runtime.h>

#define NN 100000
#define NE 1600000
#define HID 64
#define NBUK 391              // buckets of 256 node ids: (NN+255)/256
#define SRCBITS 17
#define SRCMASK 0x1FFFF
#define EBLK 2048             // edges per histogram/fill block
#define GE2 ((NE + EBLK - 1) / EBLK)        // 782 edge-blocks
#define SCANN (NBUK * GE2)    // 305,762
#define CHUNK 1024
#define NCH ((SCANN + CHUNK - 1) / CHUNK)   // 299 chunks

typedef __attribute__((ext_vector_type(8))) short bf16x8;
typedef __attribute__((ext_vector_type(4))) float f32x4;

__device__ __forceinline__ float bf2f(unsigned short u) {
    return __uint_as_float(((unsigned int)u) << 16);
}
__device__ __forceinline__ unsigned short f2bf(float f) {   // RTNE
    unsigned int x = __float_as_uint(f);
    return (unsigned short)((x + 0x7FFFu + ((x >> 16) & 1u)) >> 16);
}
__device__ __forceinline__ float bflo(unsigned int u) { return __uint_as_float(u << 16); }
__device__ __forceinline__ float bfhi(unsigned int u) { return __uint_as_float(u & 0xFFFF0000u); }

__device__ __forceinline__ int ld_idx(const int* __restrict__ ei, int off, int is64) {
    return is64 ? ei[2 * off] : ei[off];
}

// int64 edges have all-zero odd int32 words (values < 2^31). Wave-0 ballot.
__device__ __forceinline__ int detect_flag(const int* __restrict__ ei, int t, int* sflag) {
    if (t < 64) {
        unsigned long long b = __ballot(ei[2 * t + 1] != 0);
        if (t == 0) *sflag = (b == 0ULL) ? 1 : 0;  // 1 => int64 layout
    }
    __syncthreads();
    return *sflag;
}

// ---- pass A1: per-block bucket histogram (LDS atomics only) ----------------
__global__ void k_histA(const int* __restrict__ ei, int* __restrict__ histG) {
    __shared__ int hist[NBUK];
    __shared__ int sflag;
    int t = threadIdx.x;  // 256
    for (int i = t; i < NBUK; i += 256) hist[i] = 0;
    int f = detect_flag(ei, t, &sflag);   // includes __syncthreads
    int base = blockIdx.x * EBLK;
#pragma unroll
    for (int k = 0; k < EBLK / 256; ++k) {
        int e = base + k * 256 + t;
        if (e < NE) {
            int d = ld_idx(ei, NE + e, f);
            atomicAdd(&hist[d >> 8], 1);
        }
    }
    __syncthreads();
    for (int i = t; i < NBUK; i += 256) histG[i * GE2 + blockIdx.x] = hist[i];
}

// ---- 3-stage exclusive scan of SCANN counts --------------------------------
__global__ void k_scan1(int* __restrict__ g, int* __restrict__ bsum) {
    __shared__ int s[256];
    int t = threadIdx.x;
    int i4 = blockIdx.x * 256 + t;
    int base = i4 * 4;
    int4 v = make_int4(0, 0, 0, 0);
    if (base + 3 < SCANN) v = ((const int4*)g)[i4];
    else {
        if (base + 0 < SCANN) v.x = g[base + 0];
        if (base + 1 < SCANN) v.y = g[base + 1];
        if (base + 2 < SCANN) v.z = g[base + 2];
        if (base + 3 < SCANN) v.w = g[base + 3];
    }
    int tsum = v.x + v.y + v.z + v.w;
    s[t] = tsum; __syncthreads();
    for (int off = 1; off < 256; off <<= 1) {
        int u = (t >= off) ? s[t - off] : 0;
        __syncthreads();
        s[t] += u;
        __syncthreads();
    }
    int run = s[t] - tsum;
    int4 o;
    o.x = run; run += v.x;
    o.y = run; run += v.y;
    o.z = run; run += v.z;
    o.w = run;
    if (base + 3 < SCANN) ((int4*)g)[i4] = o;
    else {
        if (base + 0 < SCANN) g[base + 0] = o.x;
        if (base + 1 < SCANN) g[base + 1] = o.y;
        if (base + 2 < SCANN) g[base + 2] = o.z;
        if (base + 3 < SCANN) g[base + 3] = o.w;
    }
    if (t == 255) bsum[blockIdx.x] = s[255];
}

__global__ void k_scan2(int* __restrict__ bsum) {
    __shared__ int s[512];
    int t = threadIdx.x;  // 512
    int v = (t < NCH) ? bsum[t] : 0;
    s[t] = v; __syncthreads();
    for (int off = 1; off < 512; off <<= 1) {
        int u = (t >= off) ? s[t - off] : 0;
        __syncthreads();
        s[t] += u;
        __syncthreads();
    }
    if (t < NCH) bsum[t] = s[t] - v;
}

__global__ void k_scan3(int* __restrict__ g, const int* __restrict__ bsum) {
    int t = threadIdx.x;
    int i4 = blockIdx.x * 256 + t;
    int base = i4 * 4;
    int add = bsum[blockIdx.x];
    if (base + 3 < SCANN) {
        int4 v = ((const int4*)g)[i4];
        v.x += add; v.y += add; v.z += add; v.w += add;
        ((int4*)g)[i4] = v;
    } else {
        if (base + 0 < SCANN) g[base + 0] += add;
        if (base + 1 < SCANN) g[base + 1] += add;
        if (base + 2 < SCANN) g[base + 2] += add;
        if (base + 3 < SCANN) g[base + 3] += add;
    }
}

// ---- pass A2: place packed edges into disjoint per-(block,bucket) ranges ---
__global__ void k_fillA(const int* __restrict__ ei, const int* __restrict__ histS,
                        unsigned int* __restrict__ bbuf) {
    __shared__ int cur[NBUK];
    __shared__ int sflag;
    int t = threadIdx.x;  // 256
    for (int i = t; i < NBUK; i += 256) cur[i] = histS[i * GE2 + blockIdx.x];
    int f = detect_flag(ei, t, &sflag);   // includes __syncthreads
    int base = blockIdx.x * EBLK;
#pragma unroll
    for (int k = 0; k < EBLK / 256; ++k) {
        int e = base + k * 256 + t;
        if (e < NE) {
            int s = ld_idx(ei, e, f);
            int d = ld_idx(ei, NE + e, f);
            int p = atomicAdd(&cur[d >> 8], 1);   // LDS atomic
            bbuf[p] = ((unsigned int)(d & 255) << SRCBITS) | (unsigned int)s;
        }
    }
}

// ---- pass B: per-bucket 256-slot sort -> cnt/offs/dinv/xs + csr ------------
__global__ void k_passB(const unsigned int* __restrict__ bbuf, const int* __restrict__ histS,
                        const float* __restrict__ x,
                        int* __restrict__ cnt, int* __restrict__ offs,
                        float* __restrict__ dinv, float* __restrict__ xs,
                        int* __restrict__ csr) {
    __shared__ int hist[256];
    __shared__ int scn[256];
    __shared__ int cur[256];
    int t = threadIdx.x;  // 256
    int b = blockIdx.x;
    int base = histS[b * GE2];
    int next = (b == NBUK - 1) ? NE : histS[(b + 1) * GE2];
    int sz = next - base;
    const unsigned int* buf = bbuf + base;
    hist[t] = 0;
    __syncthreads();
    for (int e = t; e < sz; e += 256)
        atomicAdd(&hist[buf[e] >> SRCBITS], 1);
    __syncthreads();
    int deg = hist[t];
    scn[t] = deg; __syncthreads();
    for (int off = 1; off < 256; off <<= 1) {
        int u = (t >= off) ? scn[t - off] : 0;
        __syncthreads();
        scn[t] += u;
        __syncthreads();
    }
    int myoff = base + scn[t] - deg;
    int node = b * 256 + t;
    if (node < NN) {
        cnt[node]  = deg;
        offs[node] = myoff;
        float d = 1.0f / sqrtf((float)(deg + 1));
        dinv[node] = d;
        float4 xv = ((const float4*)x)[node];
        float4 o; o.x = d * xv.x; o.y = d * xv.y; o.z = d * xv.z; o.w = d * xv.w;
        ((float4*)xs)[node] = o;
    }
    cur[t] = myoff;
    __syncthreads();
    for (int e = t; e < sz; e += 256) {
        unsigned int u = buf[e];
        int p = atomicAdd(&cur[u >> SRCBITS], 1);
        csr[p] = (int)(u & SRCMASK);
    }
}

// ---- layer-1 aggregation, 8-way ILP ----------------------------------------
__global__ void k_agg1(const float* __restrict__ x, const float* __restrict__ xs,
                       const float* __restrict__ dinv, const int* __restrict__ offs,
                       const int* __restrict__ cnt, const int* __restrict__ csr,
                       float* __restrict__ agg) {
    int i = blockIdx.x * 256 + threadIdx.x;
    if (i >= NN) return;
    float sx = 0.f, sy = 0.f, sz = 0.f, sw = 0.f;
    int b = offs[i], n = cnt[i];
    int j = 0;
    for (; j + 8 <= n; j += 8) {
        int s0 = csr[b + j + 0], s1 = csr[b + j + 1], s2 = csr[b + j + 2], s3 = csr[b + j + 3];
        int s4 = csr[b + j + 4], s5 = csr[b + j + 5], s6 = csr[b + j + 6], s7 = csr[b + j + 7];
        float4 v0 = ((const float4*)xs)[s0];
        float4 v1 = ((const float4*)xs)[s1];
        float4 v2 = ((const float4*)xs)[s2];
        float4 v3 = ((const float4*)xs)[s3];
        float4 v4 = ((const float4*)xs)[s4];
        float4 v5 = ((const float4*)xs)[s5];
        float4 v6 = ((const float4*)xs)[s6];
        float4 v7 = ((const float4*)xs)[s7];
        sx += v0.x + v1.x + v2.x + v3.x + v4.x + v5.x + v6.x + v7.x;
        sy += v0.y + v1.y + v2.y + v3.y + v4.y + v5.y + v6.y + v7.y;
        sz += v0.z + v1.z + v2.z + v3.z + v4.z + v5.z + v6.z + v7.z;
        sw += v0.w + v1.w + v2.w + v3.w + v4.w + v5.w + v6.w + v7.w;
    }
    for (; j < n; ++j) {
        int s = csr[b + j];
        float4 v = ((const float4*)xs)[s];
        sx += v.x; sy += v.y; sz += v.z; sw += v.w;
    }
    float d = dinv[i];
    float4 xi = ((const float4*)x)[i];
    float4 o;
    o.x = d * (sx + d * xi.x);
    o.y = d * (sy + d * xi.y);
    o.z = d * (sz + d * xi.z);
    o.w = d * (sw + d * xi.w);
    ((float4*)agg)[i] = o;
}

// ---- h1 = relu(agg@W1+b1); hs = bf16(dinv*(h1@W2)) via MFMA ----------------
// 64 nodes/block (4 waves x 16 nodes). h1,W2 staged as bf16 in LDS (pad 72).
// mfma_f32_16x16x32_bf16: A[m=lane&15][k=quad*8+j]; B[k=quad*8+j][n=lane&15];
// D col=lane&15, row=quad*4+reg. K=64 -> 2 mfmas per 16x16 tile, 4 col-tiles.
__global__ void k_mm(const float* __restrict__ agg, const float* __restrict__ W1,
                     const float* __restrict__ b1, const float* __restrict__ W2,
                     const float* __restrict__ dinv, unsigned short* __restrict__ hs) {
    __shared__ unsigned short h1b[64 * 72];   // [localNode][k], bf16
    __shared__ unsigned short w2t[64 * 72];   // [n][k], bf16 (W2 transposed)
    __shared__ float4 sAgg[64];
    __shared__ float sW1[256];
    __shared__ float sb1[64];
    __shared__ float sDinv[64];
    int t = threadIdx.x;  // 256
    int base = blockIdx.x * 64;
    if (t < 64) {
        int g = base + t;
        sAgg[t]  = (g < NN) ? ((const float4*)agg)[g] : make_float4(0.f, 0.f, 0.f, 0.f);
        sDinv[t] = (g < NN) ? dinv[g] : 0.f;
        sb1[t]   = b1[t];
    }
    sW1[t] = W1[t];
    for (int i = t; i < 4096; i += 256) {     // W2 [k][n] fp32 -> w2t [n][k] bf16
        int k = i >> 6, n = i & 63;
        w2t[n * 72 + k] = f2bf(W2[i]);
    }
    if (blockIdx.x == 0 && t >= 128 && t < 192) hs[NN * 64 + (t - 128)] = 0;  // sentinel row
    __syncthreads();
#pragma unroll
    for (int i = 0; i < 16; ++i) {            // h1 = relu(agg@W1+b1), bf16 to LDS
        int e = t + i * 256;
        int nl = e >> 6, c = e & 63;
        float4 a = sAgg[nl];
        float h = fmaf(a.x, sW1[c], fmaf(a.y, sW1[64 + c],
                  fmaf(a.z, sW1[128 + c], fmaf(a.w, sW1[192 + c], sb1[c]))));
        h1b[nl * 72 + c] = f2bf(fmaxf(h, 0.f));
    }
    __syncthreads();
    int w = t >> 6, lane = t & 63, l15 = lane & 15, quad = lane >> 4;
    bf16x8 a0 = *(const bf16x8*)&h1b[(w * 16 + l15) * 72 + quad * 8];
    bf16x8 a1 = *(const bf16x8*)&h1b[(w * 16 + l15) * 72 + 32 + quad * 8];
    f32x4 acc[4];
#pragma unroll
    for (int nt = 0; nt < 4; ++nt) {
        bf16x8 bb0 = *(const bf16x8*)&w2t[(nt * 16 + l15) * 72 + quad * 8];
        bf16x8 bb1 = *(const bf16x8*)&w2t[(nt * 16 + l15) * 72 + 32 + quad * 8];
        f32x4 c = {0.f, 0.f, 0.f, 0.f};
        c = __builtin_amdgcn_mfma_f32_16x16x32_bf16(a0, bb0, c, 0, 0, 0);
        c = __builtin_amdgcn_mfma_f32_16x16x32_bf16(a1, bb1, c, 0, 0, 0);
        acc[nt] = c;
    }
#pragma unroll
    for (int nt = 0; nt < 4; ++nt) {
#pragma unroll
        for (int r = 0; r < 4; ++r) {
            int localn = w * 16 + quad * 4 + r;
            int g = base + localn;
            if (g < NN) hs[g * 64 + nt * 16 + l15] = f2bf(acc[nt][r] * sDinv[localn]);
        }
    }
}

// ---- layer-2 gather + head, fused, quad-row loads. One wave per node. ------
__global__ void k_gather_head(const unsigned short* __restrict__ hs, const int* __restrict__ offs,
                              const int* __restrict__ cnt, const int* __restrict__ csr,
                              const float* __restrict__ dinv, const float* __restrict__ b2,
                              const float* __restrict__ Wl, const float* __restrict__ bl,
                              float* __restrict__ out) {
    int t = threadIdx.x;
    int node = blockIdx.x * 4 + (t >> 6);
    int c = t & 63;
    int qg = c >> 4;
    int ql = c & 15;
    int b = offs[node], n = cnt[node];
    const uint2* hrow = (const uint2*)hs;        // 16 uint2 per row
    int myidx = (c < n) ? csr[b + c] : NN;       // NN = zero sentinel row
    int m = n < 64 ? n : 64;
    float4 A = make_float4(0.f, 0.f, 0.f, 0.f);
    float4 B = make_float4(0.f, 0.f, 0.f, 0.f);
    for (int j = 0; j < m; j += 16) {            // 16 edges per iter, 4 loads in flight
        int s0 = __shfl(myidx, j + qg, 64);
        int s1 = __shfl(myidx, j + 4 + qg, 64);
        int s2 = __shfl(myidx, j + 8 + qg, 64);
        int s3 = __shfl(myidx, j + 12 + qg, 64);
        uint2 u0 = hrow[s0 * 16 + ql];
        uint2 u1 = hrow[s1 * 16 + ql];
        uint2 u2 = hrow[s2 * 16 + ql];
        uint2 u3 = hrow[s3 * 16 + ql];
        A.x += bflo(u0.x); A.y += bfhi(u0.x); A.z += bflo(u0.y); A.w += bfhi(u0.y);
        B.x += bflo(u1.x); B.y += bfhi(u1.x); B.z += bflo(u1.y); B.w += bfhi(u1.y);
        A.x += bflo(u2.x); A.y += bfhi(u2.x); A.z += bflo(u2.y); A.w += bfhi(u2.y);
        B.x += bflo(u3.x); B.y += bfhi(u3.x); B.z += bflo(u3.y); B.w += bfhi(u3.y);
    }
    for (int j = 64; j < n; j += 4) {            // rare: deg > 64
        int e = j + qg;
        int s = (e < n) ? csr[b + e] : NN;
        uint2 u = hrow[s * 16 + ql];
        A.x += bflo(u.x); A.y += bfhi(u.x); A.z += bflo(u.y); A.w += bfhi(u.y);
    }
    float4 S;
    S.x = A.x + B.x; S.y = A.y + B.y; S.z = A.z + B.z; S.w = A.w + B.w;
    S.x += __shfl_xor(S.x, 16, 64); S.x += __shfl_xor(S.x, 32, 64);
    S.y += __shfl_xor(S.y, 16, 64); S.y += __shfl_xor(S.y, 32, 64);
    S.z += __shfl_xor(S.z, 16, 64); S.z += __shfl_xor(S.z, 32, 64);
    S.w += __shfl_xor(S.w, 16, 64); S.w += __shfl_xor(S.w, 32, 64);
    uint2 uS = hrow[node * 16 + ql];             // self loop, once
    S.x += bflo(uS.x); S.y += bfhi(uS.x); S.z += bflo(uS.y); S.w += bfhi(uS.y);
    float4 bv = ((const float4*)b2)[ql];
    float4 wv = ((const float4*)Wl)[ql];
    float dn = dinv[node];
    float v = fmaxf(fmaf(dn, S.x, bv.x), 0.f) * wv.x
            + fmaxf(fmaf(dn, S.y, bv.y), 0.f) * wv.y
            + fmaxf(fmaf(dn, S.z, bv.z), 0.f) * wv.z
            + fmaxf(fmaf(dn, S.w, bv.w), 0.f) * wv.w;
#pragma unroll
    for (int off = 8; off; off >>= 1) v += __shfl_down(v, off, 16);
    if (c == 0) out[node] = v + bl[0];
}

extern "C" void kernel_launch(void* const* d_in, const int* in_sizes, int n_in,
                              void* d_out, int out_size, void* d_ws, size_t ws_size,
                              hipStream_t stream) {
    const float* x  = (const float*)d_in[0];
    const int*   ei = (const int*)d_in[1];
    const float* W1 = (const float*)d_in[2];
    const float* b1 = (const float*)d_in[3];
    const float* W2 = (const float*)d_in[4];
    const float* b2 = (const float*)d_in[5];
    const float* Wl = (const float*)d_in[6];
    const float* bl = (const float*)d_in[7];
    float* out = (float*)d_out;

    char* w = (char*)d_ws;
    float* dinv  = (float*)w;                  w += NN * 4;
    int*   cnt   = (int*)w;                    w += NN * 4;
    int*   offs  = (int*)w;                    w += NN * 4;
    int*   csr   = (int*)w;                    w += NE * 4;
    float* xs    = (float*)w;                  w += NN * 4 * 4;
    float* agg   = (float*)w;                  w += NN * 4 * 4;
    unsigned short* hs = (unsigned short*)w;   w += (size_t)(NN + 1) * HID * 2;     // 12.8 MB (+sentinel)
    int*   histG = (int*)w;                    w += (size_t)((SCANN + 3) & ~3) * 4; // 1.22 MB
    int*   bsum  = (int*)w;                    w += 512 * 4;
    unsigned int* bbuf = (unsigned int*)w;     w += (size_t)NE * 4;                 // 6.4 MB

    const int GN = (NN + 255) / 256;       // 391
    const int GMM = (NN + 63) / 64;        // 1563

    hipLaunchKernelGGL(k_histA,  dim3(GE2),  dim3(256), 0, stream, ei, histG);
    hipLaunchKernelGGL(k_scan1,  dim3(NCH),  dim3(256), 0, stream, histG, bsum);
    hipLaunchKernelGGL(k_scan2,  dim3(1),    dim3(512), 0, stream, bsum);
    hipLaunchKernelGGL(k_scan3,  dim3(NCH),  dim3(256), 0, stream, histG, bsum);
    hipLaunchKernelGGL(k_fillA,  dim3(GE2),  dim3(256), 0, stream, ei, histG, bbuf);
    hipLaunchKernelGGL(k_passB,  dim3(NBUK), dim3(256), 0, stream,
                       bbuf, histG, x, cnt, offs, dinv, xs, csr);

    hipLaunchKernelGGL(k_agg1, dim3(GN), dim3(256), 0, stream,
                       x, xs, dinv, offs, cnt, csr, agg);
    hipLaunchKernelGGL(k_mm, dim3(GMM), dim3(256), 0, stream,
                       agg, W1, b1, W2, dinv, hs);
    hipLaunchKernelGGL(k_gather_head, dim3(NN / 4), dim3(256), 0, stream,
                       hs, offs, cnt, csr, dinv, b2, Wl, bl, out);
}

// Round 13
// 180.170 us; speedup vs baseline: 5.0370x; 1.0240x over previous
//
#include <hip/hip_runtime.h>

#define NN 100000
#define NE 1600000
#define HID 64
#define NBUK 391              // buckets of 256 node ids: (NN+255)/256
#define SRCBITS 17
#define SRCMASK 0x1FFFF
#define EBLK 2048             // edges per histogram/fill block
#define GE2 ((NE + EBLK - 1) / EBLK)        // 782 edge-blocks
#define SCANN (NBUK * GE2)    // 305,762
#define CHUNK 1024
#define NCH ((SCANN + CHUNK - 1) / CHUNK)   // 299 chunks

typedef __attribute__((ext_vector_type(8))) short bf16x8;
typedef __attribute__((ext_vector_type(4))) float f32x4;

__device__ __forceinline__ float bf2f(unsigned short u) {
    return __uint_as_float(((unsigned int)u) << 16);
}
__device__ __forceinline__ unsigned short f2bf(float f) {   // RTNE
    unsigned int x = __float_as_uint(f);
    return (unsigned short)((x + 0x7FFFu + ((x >> 16) & 1u)) >> 16);
}
__device__ __forceinline__ float bflo(unsigned int u) { return __uint_as_float(u << 16); }
__device__ __forceinline__ float bfhi(unsigned int u) { return __uint_as_float(u & 0xFFFF0000u); }

__device__ __forceinline__ int ld_idx(const int* __restrict__ ei, int off, int is64) {
    return is64 ? ei[2 * off] : ei[off];
}

// int64 edges have all-zero odd int32 words (values < 2^31). Wave-0 ballot.
__device__ __forceinline__ int detect_flag(const int* __restrict__ ei, int t, int* sflag) {
    if (t < 64) {
        unsigned long long b = __ballot(ei[2 * t + 1] != 0);
        if (t == 0) *sflag = (b == 0ULL) ? 1 : 0;  // 1 => int64 layout
    }
    __syncthreads();
    return *sflag;
}

// ---- pass A1: per-block bucket histogram (LDS atomics only) ----------------
__global__ void k_histA(const int* __restrict__ ei, int* __restrict__ histG) {
    __shared__ int hist[NBUK];
    __shared__ int sflag;
    int t = threadIdx.x;  // 256
    for (int i = t; i < NBUK; i += 256) hist[i] = 0;
    int f = detect_flag(ei, t, &sflag);   // includes __syncthreads
    int base = blockIdx.x * EBLK;
#pragma unroll
    for (int k = 0; k < EBLK / 256; ++k) {
        int e = base + k * 256 + t;
        if (e < NE) {
            int d = ld_idx(ei, NE + e, f);
            atomicAdd(&hist[d >> 8], 1);
        }
    }
    __syncthreads();
    for (int i = t; i < NBUK; i += 256) histG[i * GE2 + blockIdx.x] = hist[i];
}

// ---- 2-stage scan; chunk-prefix fixup is folded into consumers -------------
__global__ void k_scan1(int* __restrict__ g, int* __restrict__ bsum) {
    __shared__ int s[256];
    int t = threadIdx.x;
    int i4 = blockIdx.x * 256 + t;
    int base = i4 * 4;
    int4 v = make_int4(0, 0, 0, 0);
    if (base + 3 < SCANN) v = ((const int4*)g)[i4];
    else {
        if (base + 0 < SCANN) v.x = g[base + 0];
        if (base + 1 < SCANN) v.y = g[base + 1];
        if (base + 2 < SCANN) v.z = g[base + 2];
        if (base + 3 < SCANN) v.w = g[base + 3];
    }
    int tsum = v.x + v.y + v.z + v.w;
    s[t] = tsum; __syncthreads();
    for (int off = 1; off < 256; off <<= 1) {
        int u = (t >= off) ? s[t - off] : 0;
        __syncthreads();
        s[t] += u;
        __syncthreads();
    }
    int run = s[t] - tsum;
    int4 o;
    o.x = run; run += v.x;
    o.y = run; run += v.y;
    o.z = run; run += v.z;
    o.w = run;
    if (base + 3 < SCANN) ((int4*)g)[i4] = o;
    else {
        if (base + 0 < SCANN) g[base + 0] = o.x;
        if (base + 1 < SCANN) g[base + 1] = o.y;
        if (base + 2 < SCANN) g[base + 2] = o.z;
        if (base + 3 < SCANN) g[base + 3] = o.w;
    }
    if (t == 255) bsum[blockIdx.x] = s[255];
}

__global__ void k_scan2(int* __restrict__ bsum) {
    __shared__ int s[512];
    int t = threadIdx.x;  // 512
    int v = (t < NCH) ? bsum[t] : 0;
    s[t] = v; __syncthreads();
    for (int off = 1; off < 512; off <<= 1) {
        int u = (t >= off) ? s[t - off] : 0;
        __syncthreads();
        s[t] += u;
        __syncthreads();
    }
    if (t < NCH) bsum[t] = s[t] - v;
}

// ---- pass A2: place packed edges into disjoint per-(block,bucket) ranges ---
__global__ void k_fillA(const int* __restrict__ ei, const int* __restrict__ histS,
                        const int* __restrict__ bsum, unsigned int* __restrict__ bbuf) {
    __shared__ int cur[NBUK];
    __shared__ int sflag;
    int t = threadIdx.x;  // 256
    for (int i = t; i < NBUK; i += 256) {
        int idx = i * GE2 + blockIdx.x;
        cur[i] = histS[idx] + bsum[idx >> 10];   // fold in chunk prefix
    }
    int f = detect_flag(ei, t, &sflag);   // includes __syncthreads
    int base = blockIdx.x * EBLK;
#pragma unroll
    for (int k = 0; k < EBLK / 256; ++k) {
        int e = base + k * 256 + t;
        if (e < NE) {
            int s = ld_idx(ei, e, f);
            int d = ld_idx(ei, NE + e, f);
            int p = atomicAdd(&cur[d >> 8], 1);   // LDS atomic
            bbuf[p] = ((unsigned int)(d & 255) << SRCBITS) | (unsigned int)s;
        }
    }
}

// ---- pass B: per-bucket 256-slot sort -> cnt/offs/dinv/xs + csr ------------
__global__ void k_passB(const unsigned int* __restrict__ bbuf, const int* __restrict__ histS,
                        const int* __restrict__ bsum, const float* __restrict__ x,
                        int* __restrict__ cnt, int* __restrict__ offs,
                        float* __restrict__ dinv, float* __restrict__ xs,
                        int* __restrict__ csr) {
    __shared__ int hist[256];
    __shared__ int scn[256];
    __shared__ int cur[256];
    int t = threadIdx.x;  // 256
    int b = blockIdx.x;
    int i0 = b * GE2;
    int base = histS[i0] + bsum[i0 >> 10];
    int next = (b == NBUK - 1) ? NE : (histS[i0 + GE2] + bsum[(i0 + GE2) >> 10]);
    int sz = next - base;
    const unsigned int* buf = bbuf + base;
    hist[t] = 0;
    __syncthreads();
    for (int e = t; e < sz; e += 256)
        atomicAdd(&hist[buf[e] >> SRCBITS], 1);
    __syncthreads();
    int deg = hist[t];
    scn[t] = deg; __syncthreads();
    for (int off = 1; off < 256; off <<= 1) {
        int u = (t >= off) ? scn[t - off] : 0;
        __syncthreads();
        scn[t] += u;
        __syncthreads();
    }
    int myoff = base + scn[t] - deg;
    int node = b * 256 + t;
    if (node < NN) {
        cnt[node]  = deg;
        offs[node] = myoff;
        float d = 1.0f / sqrtf((float)(deg + 1));
        dinv[node] = d;
        float4 xv = ((const float4*)x)[node];
        float4 o; o.x = d * xv.x; o.y = d * xv.y; o.z = d * xv.z; o.w = d * xv.w;
        ((float4*)xs)[node] = o;
    }
    cur[t] = myoff;
    __syncthreads();
    for (int e = t; e < sz; e += 256) {
        unsigned int u = buf[e];
        int p = atomicAdd(&cur[u >> SRCBITS], 1);
        csr[p] = (int)(u & SRCMASK);
    }
}

// ---- fused: layer-1 aggregate (4 thr/node) + h1 + MFMA h1@W2 -> hs ---------
// 64 nodes/block, 256 threads. agg = dinv*(sum_nbr xs[s] + xs[self]).
// mfma_f32_16x16x32_bf16: A[m=lane&15][k=quad*8+j]; D col=lane&15, row=quad*4+reg.
__global__ void k_mm2(const float* __restrict__ xs, const int* __restrict__ cnt,
                      const int* __restrict__ offs, const int* __restrict__ csr,
                      const float* __restrict__ dinv,
                      const float* __restrict__ W1, const float* __restrict__ b1,
                      const float* __restrict__ W2, unsigned short* __restrict__ hs) {
    __shared__ unsigned short h1b[64 * 72];   // [localNode][k], bf16, pad 72
    __shared__ unsigned short w2t[64 * 72];   // [n][k], bf16 (W2 transposed)
    __shared__ float4 sPart[256];             // per-(part,node) partial sums
    __shared__ float4 sAgg[64];
    __shared__ float4 sXs[64];
    __shared__ float sW1[256];
    __shared__ float sb1[64];
    __shared__ float sdv[64];
    __shared__ int scnt[64];
    __shared__ int soff[64];
    int t = threadIdx.x;  // 256
    int base = blockIdx.x * 64;
    if (t < 64) {
        int g = base + t;
        bool ok = (g < NN);
        scnt[t] = ok ? cnt[g] : 0;
        soff[t] = ok ? offs[g] : 0;
        sdv[t]  = ok ? dinv[g] : 0.f;
        sXs[t]  = ok ? ((const float4*)xs)[g] : make_float4(0.f, 0.f, 0.f, 0.f);
        sb1[t]  = b1[t];
    }
    sW1[t] = W1[t];
    for (int i = t; i < 4096; i += 256) {     // W2 [k][n] fp32 -> w2t [n][k] bf16
        int k = i >> 6, n = i & 63;
        w2t[n * 72 + k] = f2bf(W2[i]);
    }
    if (blockIdx.x == 0 && t >= 128 && t < 192) hs[NN * 64 + (t - 128)] = 0;  // sentinel row
    __syncthreads();
    // aggregation: node_l = t&63, part = t>>6 handles j = part, part+4, ...
    {
        int node_l = t & 63, part = t >> 6;
        int n = scnt[node_l], b0 = soff[node_l];
        float4 s = make_float4(0.f, 0.f, 0.f, 0.f);
        int j = part;
        for (; j + 8 <= n; j += 8) {          // 2 independent loads in flight
            int s0 = csr[b0 + j], s1 = csr[b0 + j + 4];
            float4 v0 = ((const float4*)xs)[s0];
            float4 v1 = ((const float4*)xs)[s1];
            s.x += v0.x + v1.x; s.y += v0.y + v1.y;
            s.z += v0.z + v1.z; s.w += v0.w + v1.w;
        }
        for (; j < n; j += 4) {
            int s0 = csr[b0 + j];
            float4 v = ((const float4*)xs)[s0];
            s.x += v.x; s.y += v.y; s.z += v.z; s.w += v.w;
        }
        sPart[t] = s;
    }
    __syncthreads();
    if (t < 64) {
        float4 a = sPart[t], b = sPart[t + 64], c = sPart[t + 128], d = sPart[t + 192];
        float4 xi = sXs[t];
        float dn = sdv[t];
        float4 o;
        o.x = dn * (a.x + b.x + c.x + d.x + xi.x);
        o.y = dn * (a.y + b.y + c.y + d.y + xi.y);
        o.z = dn * (a.z + b.z + c.z + d.z + xi.z);
        o.w = dn * (a.w + b.w + c.w + d.w + xi.w);
        sAgg[t] = o;
    }
    __syncthreads();
#pragma unroll
    for (int i = 0; i < 16; ++i) {            // h1 = relu(agg@W1+b1), bf16 to LDS
        int e = i * 256 + t;
        int nl = e >> 6, c = e & 63;
        float4 a = sAgg[nl];
        float h = fmaf(a.x, sW1[c], fmaf(a.y, sW1[64 + c],
                  fmaf(a.z, sW1[128 + c], fmaf(a.w, sW1[192 + c], sb1[c]))));
        h1b[nl * 72 + c] = f2bf(fmaxf(h, 0.f));
    }
    __syncthreads();
    int w = t >> 6, lane = t & 63, l15 = lane & 15, quad = lane >> 4;
    bf16x8 a0 = *(const bf16x8*)&h1b[(w * 16 + l15) * 72 + quad * 8];
    bf16x8 a1 = *(const bf16x8*)&h1b[(w * 16 + l15) * 72 + 32 + quad * 8];
    f32x4 acc[4];
#pragma unroll
    for (int nt = 0; nt < 4; ++nt) {
        bf16x8 bb0 = *(const bf16x8*)&w2t[(nt * 16 + l15) * 72 + quad * 8];
        bf16x8 bb1 = *(const bf16x8*)&w2t[(nt * 16 + l15) * 72 + 32 + quad * 8];
        f32x4 c = {0.f, 0.f, 0.f, 0.f};
        c = __builtin_amdgcn_mfma_f32_16x16x32_bf16(a0, bb0, c, 0, 0, 0);
        c = __builtin_amdgcn_mfma_f32_16x16x32_bf16(a1, bb1, c, 0, 0, 0);
        acc[nt] = c;
    }
#pragma unroll
    for (int nt = 0; nt < 4; ++nt) {
#pragma unroll
        for (int r = 0; r < 4; ++r) {
            int localn = w * 16 + quad * 4 + r;
            int g = base + localn;
            if (g < NN) hs[g * 64 + nt * 16 + l15] = f2bf(acc[nt][r] * sdv[localn]);
        }
    }
}

// ---- layer-2 gather + head, fused, quad-row loads. One wave per node. ------
__global__ void k_gather_head(const unsigned short* __restrict__ hs, const int* __restrict__ offs,
                              const int* __restrict__ cnt, const int* __restrict__ csr,
                              const float* __restrict__ dinv, const float* __restrict__ b2,
                              const float* __restrict__ Wl, const float* __restrict__ bl,
                              float* __restrict__ out) {
    int t = threadIdx.x;
    int node = blockIdx.x * 4 + (t >> 6);
    int c = t & 63;
    int qg = c >> 4;
    int ql = c & 15;
    int b = offs[node], n = cnt[node];
    const uint2* hrow = (const uint2*)hs;        // 16 uint2 per row
    int myidx = (c < n) ? csr[b + c] : NN;       // NN = zero sentinel row
    int m = n < 64 ? n : 64;
    float4 A = make_float4(0.f, 0.f, 0.f, 0.f);
    float4 B = make_float4(0.f, 0.f, 0.f, 0.f);
    for (int j = 0; j < m; j += 16) {            // 16 edges per iter, 4 loads in flight
        int s0 = __shfl(myidx, j + qg, 64);
        int s1 = __shfl(myidx, j + 4 + qg, 64);
        int s2 = __shfl(myidx, j + 8 + qg, 64);
        int s3 = __shfl(myidx, j + 12 + qg, 64);
        uint2 u0 = hrow[s0 * 16 + ql];
        uint2 u1 = hrow[s1 * 16 + ql];
        uint2 u2 = hrow[s2 * 16 + ql];
        uint2 u3 = hrow[s3 * 16 + ql];
        A.x += bflo(u0.x); A.y += bfhi(u0.x); A.z += bflo(u0.y); A.w += bfhi(u0.y);
        B.x += bflo(u1.x); B.y += bfhi(u1.x); B.z += bflo(u1.y); B.w += bfhi(u1.y);
        A.x += bflo(u2.x); A.y += bfhi(u2.x); A.z += bflo(u2.y); A.w += bfhi(u2.y);
        B.x += bflo(u3.x); B.y += bfhi(u3.x); B.z += bflo(u3.y); B.w += bfhi(u3.y);
    }
    for (int j = 64; j < n; j += 4) {            // rare: deg > 64
        int e = j + qg;
        int s = (e < n) ? csr[b + e] : NN;
        uint2 u = hrow[s * 16 + ql];
        A.x += bflo(u.x); A.y += bfhi(u.x); A.z += bflo(u.y); A.w += bfhi(u.y);
    }
    float4 S;
    S.x = A.x + B.x; S.y = A.y + B.y; S.z = A.z + B.z; S.w = A.w + B.w;
    S.x += __shfl_xor(S.x, 16, 64); S.x += __shfl_xor(S.x, 32, 64);
    S.y += __shfl_xor(S.y, 16, 64); S.y += __shfl_xor(S.y, 32, 64);
    S.z += __shfl_xor(S.z, 16, 64); S.z += __shfl_xor(S.z, 32, 64);
    S.w += __shfl_xor(S.w, 16, 64); S.w += __shfl_xor(S.w, 32, 64);
    uint2 uS = hrow[node * 16 + ql];             // self loop, once
    S.x += bflo(uS.x); S.y += bfhi(uS.x); S.z += bflo(uS.y); S.w += bfhi(uS.y);
    float4 bv = ((const float4*)b2)[ql];
    float4 wv = ((const float4*)Wl)[ql];
    float dn = dinv[node];
    float v = fmaxf(fmaf(dn, S.x, bv.x), 0.f) * wv.x
            + fmaxf(fmaf(dn, S.y, bv.y), 0.f) * wv.y
            + fmaxf(fmaf(dn, S.z, bv.z), 0.f) * wv.z
            + fmaxf(fmaf(dn, S.w, bv.w), 0.f) * wv.w;
#pragma unroll
    for (int off = 8; off; off >>= 1) v += __shfl_down(v, off, 16);
    if (c == 0) out[node] = v + bl[0];
}

extern "C" void kernel_launch(void* const* d_in, const int* in_sizes, int n_in,
                              void* d_out, int out_size, void* d_ws, size_t ws_size,
                              hipStream_t stream) {
    const float* x  = (const float*)d_in[0];
    const int*   ei = (const int*)d_in[1];
    const float* W1 = (const float*)d_in[2];
    const float* b1 = (const float*)d_in[3];
    const float* W2 = (const float*)d_in[4];
    const float* b2 = (const float*)d_in[5];
    const float* Wl = (const float*)d_in[6];
    const float* bl = (const float*)d_in[7];
    float* out = (float*)d_out;

    char* w = (char*)d_ws;
    float* dinv  = (float*)w;                  w += NN * 4;
    int*   cnt   = (int*)w;                    w += NN * 4;
    int*   offs  = (int*)w;                    w += NN * 4;
    int*   csr   = (int*)w;                    w += NE * 4;
    float* xs    = (float*)w;                  w += NN * 4 * 4;
    unsigned short* hs = (unsigned short*)w;   w += (size_t)(NN + 1) * HID * 2;     // 12.8 MB (+sentinel)
    int*   histG = (int*)w;                    w += (size_t)((SCANN + 3) & ~3) * 4; // 1.22 MB
    int*   bsum  = (int*)w;                    w += 512 * 4;
    unsigned int* bbuf = (unsigned int*)w;     w += (size_t)NE * 4;                 // 6.4 MB

    const int GMM = (NN + 63) / 64;        // 1563

    hipLaunchKernelGGL(k_histA,  dim3(GE2),  dim3(256), 0, stream, ei, histG);
    hipLaunchKernelGGL(k_scan1,  dim3(NCH),  dim3(256), 0, stream, histG, bsum);
    hipLaunchKernelGGL(k_scan2,  dim3(1),    dim3(512), 0, stream, bsum);
    hipLaunchKernelGGL(k_fillA,  dim3(GE2),  dim3(256), 0, stream, ei, histG, bsum, bbuf);
    hipLaunchKernelGGL(k_passB,  dim3(NBUK), dim3(256), 0, stream,
                       bbuf, histG, bsum, x, cnt, offs, dinv, xs, csr);
    hipLaunchKernelGGL(k_mm2, dim3(GMM), dim3(256), 0, stream,
                       xs, cnt, offs, csr, dinv, W1, b1, W2, hs);
    hipLaunchKernelGGL(k_gather_head, dim3(NN / 4), dim3(256), 0, stream,
                       hs, offs, cnt, csr, dinv, b2, Wl, bl, out);
}